// Round 1
// baseline (413.221 us; speedup 1.0000x reference)
//
#include <hip/hip_runtime.h>
#include <hip/hip_bf16.h>
#include <stdint.h>

// Problem constants
#define Bc 4
#define Sc 2048
#define Ec 512
#define Hc 8
#define Dc 64
#define HDc 512

typedef __attribute__((ext_vector_type(8))) short bf16x8;
typedef __attribute__((ext_vector_type(4))) float f32x4;

// round-to-nearest-even fp32 -> bf16
__device__ __forceinline__ unsigned short f2bf(float x) {
    union { float f; unsigned u; } v; v.f = x;
    unsigned r = v.u + 0x7FFFu + ((v.u >> 16) & 1u);
    return (unsigned short)(r >> 16);
}

__device__ __forceinline__ uint4 pack8(float4 a, float4 b) {
    union { unsigned short us[8]; uint4 v; } u;
    u.us[0] = f2bf(a.x); u.us[1] = f2bf(a.y); u.us[2] = f2bf(a.z); u.us[3] = f2bf(a.w);
    u.us[4] = f2bf(b.x); u.us[5] = f2bf(b.y); u.us[6] = f2bf(b.z); u.us[7] = f2bf(b.w);
    return u.v;
}

// ---------------------------------------------------------------------------
// Kernel 1: pack int32 mask (B,S,S) into bits. word w covers flat elems [64w, 64w+64).
__global__ __launch_bounds__(256) void pack_mask(const int* __restrict__ mask,
                                                 unsigned long long* __restrict__ bits) {
    const int lane = threadIdx.x & 63;
    int wave = (blockIdx.x * blockDim.x + threadIdx.x) >> 6;
    const int nwaves = (gridDim.x * blockDim.x) >> 6;
    const int nwords = (Bc * Sc * Sc) / 64;
    for (int w = wave; w < nwords; w += nwaves) {
        int m = mask[(size_t)w * 64 + lane];
        unsigned long long b = __ballot(m != 0);
        if (lane == 0) bits[w] = b;
    }
}

// ---------------------------------------------------------------------------
// Kernel 2: QKV projection GEMM. X (8192x512 fp32) @ W (512x512 fp32) + bias
// -> bf16 out (8192x512) row-major. grid.z selects q/k/v.
__global__ __launch_bounds__(256) void proj_gemm(
    const float* __restrict__ Xq, const float* __restrict__ Xk, const float* __restrict__ Xv,
    const float* __restrict__ Wq, const float* __restrict__ Wk, const float* __restrict__ Wv,
    const float* __restrict__ bq, const float* __restrict__ bk, const float* __restrict__ bv,
    unsigned short* __restrict__ Oq, unsigned short* __restrict__ Ok, unsigned short* __restrict__ Ov)
{
    const int z = blockIdx.z;
    const float* X    = z == 0 ? Xq : (z == 1 ? Xk : Xv);
    const float* W    = z == 0 ? Wq : (z == 1 ? Wk : Wv);
    const float* bias = z == 0 ? bq : (z == 1 ? bk : bv);
    unsigned short* O = z == 0 ? Oq : (z == 1 ? Ok : Ov);

    const int m0 = blockIdx.x * 64;
    const int n0 = blockIdx.y * 64;
    const int tid = threadIdx.x;
    const int lane = tid & 63;
    const int w = tid >> 6;

    __shared__ unsigned short As[64 * 64]; // [m][k], xor-swizzled 8-elem groups
    __shared__ unsigned short Bs[64 * 64]; // [n][k] (transposed), swizzled

    f32x4 acc[4];
#pragma unroll
    for (int i = 0; i < 4; i++) acc[i] = (f32x4){0.f, 0.f, 0.f, 0.f};

    for (int k0 = 0; k0 < Ec; k0 += 64) {
        __syncthreads();
        // stage A: rows m0..m0+63, cols k0..k0+63, fp32 -> bf16
#pragma unroll
        for (int c = 0; c < 2; c++) {
            int g = tid + 256 * c;
            int row = g >> 3, kg = g & 7;
            const float* src = X + (size_t)(m0 + row) * Ec + k0 + kg * 8;
            float4 fa = *(const float4*)src;
            float4 fb = *(const float4*)(src + 4);
            *(uint4*)&As[row * 64 + ((kg ^ (row & 7)) * 8)] = pack8(fa, fb);
        }
        // stage B transposed: W rows k0..k0+63, cols n0..n0+63 -> Bs[n][k]
#pragma unroll
        for (int c = 0; c < 2; c++) {
            int g = tid + 256 * c;
            int kr = g >> 3, ng = g & 7;
            const float* src = W + (size_t)(k0 + kr) * HDc + n0 + ng * 8;
            union { float4 v[2]; float f[8]; } t;
            t.v[0] = *(const float4*)src;
            t.v[1] = *(const float4*)(src + 4);
#pragma unroll
            for (int i = 0; i < 8; i++) {
                int n = ng * 8 + i;
                Bs[n * 64 + (((kr >> 3) ^ (n & 7)) * 8) + (kr & 7)] = f2bf(t.f[i]);
            }
        }
        __syncthreads();
#pragma unroll
        for (int ks = 0; ks < 2; ks++) {
            int arow = 16 * w + (lane & 15);
            int kg = ks * 4 + (lane >> 4);
            bf16x8 a = *(const bf16x8*)&As[arow * 64 + ((kg ^ (arow & 7)) * 8)];
#pragma unroll
            for (int nt = 0; nt < 4; nt++) {
                int brow = nt * 16 + (lane & 15);
                bf16x8 bfr = *(const bf16x8*)&Bs[brow * 64 + ((kg ^ (brow & 7)) * 8)];
                acc[nt] = __builtin_amdgcn_mfma_f32_16x16x32_bf16(a, bfr, acc[nt], 0, 0, 0);
            }
        }
    }
    // epilogue: C row = (lane>>4)*4 + r (within 16-row strip), col = nt*16 + (lane&15)
#pragma unroll
    for (int nt = 0; nt < 4; nt++) {
#pragma unroll
        for (int r = 0; r < 4; r++) {
            int gm = m0 + 16 * w + (lane >> 4) * 4 + r;
            int gn = n0 + nt * 16 + (lane & 15);
            O[(size_t)gm * HDc + gn] = f2bf(acc[nt][r] + bias[gn]);
        }
    }
}

// ---------------------------------------------------------------------------
// Kernel 3: flash attention. One block = (b, h, 64-row Q tile). Online softmax.
__global__ __launch_bounds__(256) void attn_kernel(
    const unsigned short* __restrict__ Qb, const unsigned short* __restrict__ Kb,
    const unsigned short* __restrict__ Vb, const unsigned long long* __restrict__ Mb,
    unsigned short* __restrict__ Ob)
{
    const int qt = blockIdx.x;   // 0..31
    const int h  = blockIdx.y;   // 0..7
    const int b  = blockIdx.z;   // 0..3
    const int q0 = qt * 64;
    const int tid = threadIdx.x, lane = tid & 63, w = tid >> 6;

    __shared__ unsigned short Qs[64 * 64]; // [q][d] swizzled
    __shared__ unsigned short Ks[64 * 64]; // [tok][d] swizzled
    __shared__ unsigned short Vs[64 * 64]; // [d][tok] (transposed) swizzled
    __shared__ unsigned short Ps[64 * 64]; // [q][tok] swizzled, wave-private strips

    const size_t baseQ  = ((size_t)b * Sc + q0) * HDc + h * Dc;
    const size_t baseKV = ((size_t)b * Sc) * HDc + h * Dc;
    const unsigned long long* mrow = Mb + ((size_t)b * Sc + q0) * (Sc / 64);

    // stage Q once
#pragma unroll
    for (int c = 0; c < 2; c++) {
        int g = tid + 256 * c;
        int row = g >> 3, dg = g & 7;
        uint4 v = *(const uint4*)(Qb + baseQ + (size_t)row * HDc + dg * 8);
        *(uint4*)&Qs[row * 64 + ((dg ^ (row & 7)) * 8)] = v;
    }

    f32x4 o_acc[4];
#pragma unroll
    for (int i = 0; i < 4; i++) o_acc[i] = (f32x4){0.f, 0.f, 0.f, 0.f};
    float m_i[4], l_i[4];
#pragma unroll
    for (int r = 0; r < 4; r++) { m_i[r] = -3.0e38f; l_i[r] = 0.f; }

    for (int kt = 0; kt < Sc / 64; kt++) {
        __syncthreads();
        // stage K tile (row-major [tok][d])
#pragma unroll
        for (int c = 0; c < 2; c++) {
            int g = tid + 256 * c;
            int row = g >> 3, dg = g & 7;
            uint4 v = *(const uint4*)(Kb + baseKV + (size_t)(kt * 64 + row) * HDc + dg * 8);
            *(uint4*)&Ks[row * 64 + ((dg ^ (row & 7)) * 8)] = v;
        }
        // stage V transposed ([d][tok])
#pragma unroll
        for (int c = 0; c < 2; c++) {
            int g = tid + 256 * c;
            int tok = g >> 3, dg = g & 7;
            union { uint4 v; unsigned short us[8]; } u;
            u.v = *(const uint4*)(Vb + baseKV + (size_t)(kt * 64 + tok) * HDc + dg * 8);
#pragma unroll
            for (int i = 0; i < 8; i++) {
                int d = dg * 8 + i;
                Vs[d * 64 + (((tok >> 3) ^ (d & 7)) * 8) + (tok & 7)] = u.us[i];
            }
        }
        __syncthreads();

        // S = Q K^T  (64x64 tile; wave w owns rows 16w..16w+15)
        f32x4 sc[4];
#pragma unroll
        for (int nt = 0; nt < 4; nt++) sc[nt] = (f32x4){0.f, 0.f, 0.f, 0.f};
#pragma unroll
        for (int ks = 0; ks < 2; ks++) {
            int arow = 16 * w + (lane & 15);
            int kg = ks * 4 + (lane >> 4);
            bf16x8 a = *(const bf16x8*)&Qs[arow * 64 + ((kg ^ (arow & 7)) * 8)];
#pragma unroll
            for (int nt = 0; nt < 4; nt++) {
                int brow = nt * 16 + (lane & 15);
                bf16x8 bfr = *(const bf16x8*)&Ks[brow * 64 + ((kg ^ (brow & 7)) * 8)];
                sc[nt] = __builtin_amdgcn_mfma_f32_16x16x32_bf16(a, bfr, sc[nt], 0, 0, 0);
            }
        }

        // mask + online softmax (per C-row r; 16 lanes of a quad-group share rows)
#pragma unroll
        for (int r = 0; r < 4; r++) {
            int qrow = 16 * w + (lane >> 4) * 4 + r;
            unsigned long long mw = mrow[(size_t)qrow * (Sc / 64) + kt];
            float lg[4];
            float mx = -3.0e38f;
#pragma unroll
            for (int nt = 0; nt < 4; nt++) {
                int bit = (int)((mw >> (nt * 16 + (lane & 15))) & 1ull);
                lg[nt] = bit ? sc[nt][r] * 0.125f : -1.25e8f;
                mx = fmaxf(mx, lg[nt]);
            }
#pragma unroll
            for (int s = 1; s < 16; s <<= 1) mx = fmaxf(mx, __shfl_xor(mx, s, 64));
            float mnew = fmaxf(m_i[r], mx);
            float alpha = __expf(m_i[r] - mnew);
            float psum = 0.f;
#pragma unroll
            for (int nt = 0; nt < 4; nt++) {
                float p = __expf(lg[nt] - mnew);
                psum += p;
                int col = nt * 16 + (lane & 15);
                Ps[qrow * 64 + (((col >> 3) ^ (qrow & 7)) * 8) + (col & 7)] = f2bf(p);
            }
#pragma unroll
            for (int s = 1; s < 16; s <<= 1) psum += __shfl_xor(psum, s, 64);
            l_i[r] = l_i[r] * alpha + psum;
            m_i[r] = mnew;
#pragma unroll
            for (int nt = 0; nt < 4; nt++) o_acc[nt][r] *= alpha;
        }

        // O += P V  (P strip is wave-private; same-wave LDS ops are ordered)
#pragma unroll
        for (int ks = 0; ks < 2; ks++) {
            int arow = 16 * w + (lane & 15);
            int kg = ks * 4 + (lane >> 4);
            bf16x8 a = *(const bf16x8*)&Ps[arow * 64 + ((kg ^ (arow & 7)) * 8)];
#pragma unroll
            for (int nt = 0; nt < 4; nt++) {
                int drow = nt * 16 + (lane & 15);
                bf16x8 bfr = *(const bf16x8*)&Vs[drow * 64 + ((kg ^ (drow & 7)) * 8)];
                o_acc[nt] = __builtin_amdgcn_mfma_f32_16x16x32_bf16(a, bfr, o_acc[nt], 0, 0, 0);
            }
        }
    }

    // epilogue: normalize and store attn output bf16 (B,S,HD) at head column h*64
    const size_t baseO = ((size_t)b * Sc + q0) * HDc + h * Dc;
#pragma unroll
    for (int r = 0; r < 4; r++) {
        float inv = 1.0f / l_i[r];
        int qrow = 16 * w + (lane >> 4) * 4 + r;
#pragma unroll
        for (int nt = 0; nt < 4; nt++) {
            int col = nt * 16 + (lane & 15);
            Ob[baseO + (size_t)qrow * HDc + col] = f2bf(o_acc[nt][r] * inv);
        }
    }
}

// ---------------------------------------------------------------------------
// Kernel 4: output projection. A (8192x512 bf16) @ wo (512x512 fp32) + bo -> fp32 out.
__global__ __launch_bounds__(256) void out_gemm(
    const unsigned short* __restrict__ Abf, const float* __restrict__ W,
    const float* __restrict__ bias, float* __restrict__ Out)
{
    const int m0 = blockIdx.x * 64;
    const int n0 = blockIdx.y * 64;
    const int tid = threadIdx.x;
    const int lane = tid & 63;
    const int w = tid >> 6;

    __shared__ unsigned short As[64 * 64];
    __shared__ unsigned short Bs[64 * 64];

    f32x4 acc[4];
#pragma unroll
    for (int i = 0; i < 4; i++) acc[i] = (f32x4){0.f, 0.f, 0.f, 0.f};

    for (int k0 = 0; k0 < HDc; k0 += 64) {
        __syncthreads();
#pragma unroll
        for (int c = 0; c < 2; c++) {
            int g = tid + 256 * c;
            int row = g >> 3, kg = g & 7;
            uint4 v = *(const uint4*)(Abf + (size_t)(m0 + row) * HDc + k0 + kg * 8);
            *(uint4*)&As[row * 64 + ((kg ^ (row & 7)) * 8)] = v;
        }
#pragma unroll
        for (int c = 0; c < 2; c++) {
            int g = tid + 256 * c;
            int kr = g >> 3, ng = g & 7;
            const float* src = W + (size_t)(k0 + kr) * Ec + n0 + ng * 8;
            union { float4 v[2]; float f[8]; } t;
            t.v[0] = *(const float4*)src;
            t.v[1] = *(const float4*)(src + 4);
#pragma unroll
            for (int i = 0; i < 8; i++) {
                int n = ng * 8 + i;
                Bs[n * 64 + (((kr >> 3) ^ (n & 7)) * 8) + (kr & 7)] = f2bf(t.f[i]);
            }
        }
        __syncthreads();
#pragma unroll
        for (int ks = 0; ks < 2; ks++) {
            int arow = 16 * w + (lane & 15);
            int kg = ks * 4 + (lane >> 4);
            bf16x8 a = *(const bf16x8*)&As[arow * 64 + ((kg ^ (arow & 7)) * 8)];
#pragma unroll
            for (int nt = 0; nt < 4; nt++) {
                int brow = nt * 16 + (lane & 15);
                bf16x8 bfr = *(const bf16x8*)&Bs[brow * 64 + ((kg ^ (brow & 7)) * 8)];
                acc[nt] = __builtin_amdgcn_mfma_f32_16x16x32_bf16(a, bfr, acc[nt], 0, 0, 0);
            }
        }
    }
#pragma unroll
    for (int nt = 0; nt < 4; nt++) {
#pragma unroll
        for (int r = 0; r < 4; r++) {
            int gm = m0 + 16 * w + (lane >> 4) * 4 + r;
            int gn = n0 + nt * 16 + (lane & 15);
            Out[(size_t)gm * Ec + gn] = acc[nt][r] + bias[gn];
        }
    }
}

// ---------------------------------------------------------------------------
extern "C" void kernel_launch(void* const* d_in, const int* in_sizes, int n_in,
                              void* d_out, int out_size, void* d_ws, size_t ws_size,
                              hipStream_t stream)
{
    const float* xq = (const float*)d_in[0];
    const float* xk = (const float*)d_in[1];
    const float* xv = (const float*)d_in[2];
    const int* mask = (const int*)d_in[3];
    const float* wq = (const float*)d_in[4];
    const float* bq = (const float*)d_in[5];
    const float* wk = (const float*)d_in[6];
    const float* bk = (const float*)d_in[7];
    const float* wv = (const float*)d_in[8];
    const float* bv = (const float*)d_in[9];
    const float* wo = (const float*)d_in[10];
    const float* bo = (const float*)d_in[11];
    float* out = (float*)d_out;

    char* ws = (char*)d_ws;
    unsigned short* qb = (unsigned short*)(ws + (size_t)0 * 1024 * 1024);
    unsigned short* kb = (unsigned short*)(ws + (size_t)8 * 1024 * 1024);
    unsigned short* vb = (unsigned short*)(ws + (size_t)16 * 1024 * 1024);
    unsigned short* ab = (unsigned short*)(ws + (size_t)24 * 1024 * 1024);
    unsigned long long* mb = (unsigned long long*)(ws + (size_t)32 * 1024 * 1024);

    hipLaunchKernelGGL(pack_mask, dim3(2048), dim3(256), 0, stream, mask, mb);
    hipLaunchKernelGGL(proj_gemm, dim3(128, 8, 3), dim3(256), 0, stream,
                       xq, xk, xv, wq, wk, wv, bq, bk, bv, qb, kb, vb);
    hipLaunchKernelGGL(attn_kernel, dim3(32, 8, 4), dim3(256), 0, stream,
                       qb, kb, vb, mb, ab);
    hipLaunchKernelGGL(out_gemm, dim3(128, 8), dim3(256), 0, stream, ab, wo, bo, out);
}